// Round 4
// baseline (6415.513 us; speedup 1.0000x reference)
//
#include <hip/hip_runtime.h>

typedef unsigned short u16;
typedef unsigned u32;
typedef unsigned long long u64;
typedef __bf16 bf16x8 __attribute__((ext_vector_type(8)));
typedef u16 u16x8 __attribute__((ext_vector_type(8)));
typedef u16 u16x4 __attribute__((ext_vector_type(4)));
typedef u32 u32x4 __attribute__((ext_vector_type(4)));
typedef float f32x4 __attribute__((ext_vector_type(4)));

__device__ __forceinline__ u16 f2bf(float f){
    unsigned u = __builtin_bit_cast(unsigned, f);
    u = (u + 0x7fffu + ((u >> 16) & 1u)) >> 16;
    return (u16)u;
}
__device__ __forceinline__ float bf2f(u16 h){
    unsigned u = ((unsigned)h) << 16;
    return __builtin_bit_cast(float, u);
}
__device__ __forceinline__ float sigmoidf_(float x){ return 1.0f / (1.0f + __expf(-x)); }
__device__ __forceinline__ float tanhf_(float x){
    float e = __expf(2.0f * x);
    return 1.0f - 2.0f / (e + 1.0f);
}
__device__ __forceinline__ u64 aload64(const u64* p){
    return __hip_atomic_load(p, __ATOMIC_RELAXED, __HIP_MEMORY_SCOPE_AGENT);
}

// ---------------------------------------------------------------------------
// Kernel 0: pack Wx transposed gate-interleaved bf16 (pk = 4*hcol+gate), and
// clear all h-exchange words to value=0, TAG=0xFFFF (low halfword!) — a tag
// no real step (0..1023) and no 0xAA poison (tag 0xAAAA) can ever match.
// ---------------------------------------------------------------------------
__global__ __launch_bounds__(256) void lstm_pack(
    const float* __restrict__ Wgx, const float* __restrict__ Wix,
    const float* __restrict__ Wfx, const float* __restrict__ Wox,
    u16* __restrict__ Wxpt, u32* __restrict__ h32)
{
    int idx = blockIdx.x * 256 + threadIdx.x;   // 512*256 = 131072 threads
    // clear tags: h32 is [2][16][16][256] u32 = 131072 words
    __hip_atomic_store(h32 + idx, 0x0000FFFFu,
                       __ATOMIC_RELAXED, __HIP_MEMORY_SCOPE_AGENT);
    const float* W4[4] = {Wgx, Wix, Wfx, Wox};
    if (idx < 1024 * 128){
        int pk = idx >> 7, k = idx & 127;
        int g = pk & 3, h = pk >> 2;
        Wxpt[idx] = f2bf(W4[g][k * 256 + h]);
    }
}

// ---------------------------------------------------------------------------
// Kernel 1: xg GEMM (unchanged, proven): xg[row][pk] bf16,
// row = t_local*256 + b, pk gate-interleaved.
// ---------------------------------------------------------------------------
__global__ __launch_bounds__(256, 2) void lstm_xg(
    const float* __restrict__ x, const u16* __restrict__ Wxpt,
    u16* __restrict__ xg, int ct0, int steps, int mtiles_total)
{
    __shared__ u16 Bt[32768];
    const int tid = threadIdx.x;
    const int n0 = blockIdx.y << 8;

    for (int ii = 0; ii < 16; ++ii){
        int cid = ii * 256 + tid;
        int nn = cid >> 4;
        int kc = (cid & 15) << 3;
        u16x8 v = *(const u16x8*)(Wxpt + (size_t)(n0 + nn) * 128 + kc);
        unsigned byte = (unsigned)(nn << 8) + (unsigned)(kc << 1);
        byte ^= ((nn & 7) << 4);
        *(u16x8*)((char*)Bt + byte) = v;
    }
    __syncthreads();

    const int w = tid >> 6, l = tid & 63;
    const int l15 = l & 15, l4 = l >> 4;

    for (int i = 0; i < 16; ++i){
        int mtile = blockIdx.x * 16 + i;
        if (mtile >= mtiles_total) break;
        int row = (mtile << 6) + (w << 4) + l15;
        int t_glob = ct0 + (row >> 8);
        int b = row & 255;
        const float* xr = x + ((size_t)b * 1024 + t_glob) * 128;

        f32x4 acc[16];
        #pragma unroll
        for (int nt = 0; nt < 16; ++nt) acc[nt] = (f32x4){0.f, 0.f, 0.f, 0.f};

        #pragma unroll
        for (int kf = 0; kf < 4; ++kf){
            int k0 = kf * 32 + l4 * 8;
            f32x4 xa = *(const f32x4*)(xr + k0);
            f32x4 xb = *(const f32x4*)(xr + k0 + 4);
            u16x8 bu;
            bu[0]=f2bf(xa[0]); bu[1]=f2bf(xa[1]); bu[2]=f2bf(xa[2]); bu[3]=f2bf(xa[3]);
            bu[4]=f2bf(xb[0]); bu[5]=f2bf(xb[1]); bu[6]=f2bf(xb[2]); bu[7]=f2bf(xb[3]);
            bf16x8 bfX = __builtin_bit_cast(bf16x8, bu);
            #pragma unroll
            for (int nt = 0; nt < 16; ++nt){
                int nn = (nt << 4) + l15;
                unsigned byte = (unsigned)(nn << 8) + (unsigned)(k0 << 1);
                byte ^= ((nn & 7) << 4);
                u16x8 au = *(const u16x8*)((const char*)Bt + byte);
                bf16x8 afW = __builtin_bit_cast(bf16x8, au);
                acc[nt] = __builtin_amdgcn_mfma_f32_16x16x32_bf16(afW, bfX, acc[nt], 0, 0, 0);
            }
        }
        #pragma unroll
        for (int nt = 0; nt < 16; ++nt){
            u16x4 o;
            o[0]=f2bf(acc[nt][0]); o[1]=f2bf(acc[nt][1]);
            o[2]=f2bf(acc[nt][2]); o[3]=f2bf(acc[nt][3]);
            *(u16x4*)(xg + (size_t)row * 1024 + n0 + (nt << 4) + (l4 << 2)) = o;
        }
    }
}

// ---------------------------------------------------------------------------
// Kernel 2: recurrent scan. Grid 128 = 16 row-groups x 8 col-blocks, 512 thr.
// Block (mb,nb): rows [16mb,16mb+16), pk [128nb,128nb+128) (32 hcols).
// h exchange: tagged u32 words (bf16(h)<<16 | t) via relaxed agent atomics —
// the cooperative stage load IS the sync (retry until all tags == t-1).
// Staged once per block into LDS (rotation layout), waves ds_read fragments.
// 2-term MFMA: a0 = whi*h, a1 = wlo*h (h single bf16 on the wire).
// ---------------------------------------------------------------------------
__global__ __launch_bounds__(512, 1) void lstm_rec(
    const u16* __restrict__ xg,
    const float* __restrict__ Wgh, const float* __restrict__ Wih,
    const float* __restrict__ Wfh, const float* __restrict__ Woh,
    const float* __restrict__ bgx, const float* __restrict__ bgh,
    const float* __restrict__ bix, const float* __restrict__ bih,
    const float* __restrict__ bfx, const float* __restrict__ bfh,
    const float* __restrict__ box, const float* __restrict__ boh,
    u32* __restrict__ h32,
    float* __restrict__ c_ws, float* __restrict__ hT, int ct0, int steps)
{
    __shared__ char lds[16384];   // 2 x [16 rows][512B] staged bf16 h
    const int tid = threadIdx.x;
    const int w = tid >> 6, l = tid & 63;
    const int l15 = l & 15, l4 = l >> 4;
    const int mb = blockIdx.x & 15, nb = blockIdx.x >> 4;
    const int P0 = (nb << 7) + (w << 4);        // wave's packed-col base

    // ---- one-time: Wh^T fragments (hi/lo split) into VGPRs ----
    const float* Wh4[4] = {Wgh, Wih, Wfh, Woh};
    int pkA = P0 + l15;
    const float* Wcol = Wh4[pkA & 3] + (pkA >> 2);
    bf16x8 whi[8], wlo[8];
    #pragma unroll
    for (int kf = 0; kf < 8; ++kf){
        u16x8 hi8, lo8;
        #pragma unroll
        for (int j = 0; j < 8; ++j){
            float v = Wcol[(size_t)(kf * 32 + l4 * 8 + j) * 256];
            u16 h = f2bf(v);
            hi8[j] = h;
            lo8[j] = f2bf(v - bf2f(h));
        }
        whi[kf] = __builtin_bit_cast(bf16x8, hi8);
        wlo[kf] = __builtin_bit_cast(bf16x8, lo8);
    }
    // ---- bias (bx+bh folded), c state ----
    const int hc = (P0 >> 2) + l4;              // lane's h column (global)
    const int r  = (mb << 4) + l15;             // lane's batch row (global)
    const float* bx4[4] = {bgx, bix, bfx, box};
    const float* bh4[4] = {bgh, bih, bfh, boh};
    float bias[4];
    #pragma unroll
    for (int g2 = 0; g2 < 4; ++g2) bias[g2] = bx4[g2][hc] + bh4[g2][hc];
    float c_val = 0.f;
    if (ct0 > 0) c_val = c_ws[(r << 8) + hc];

    // ---- stage-load identity: thread covers (row_s, 8 cols) of group h ----
    const int row_s = tid >> 5;                 // 0..15
    const int cidx  = tid & 31;                 // col-octet index
    const u32* gb = h32 + mb * 4096;            // group base (u32)
    u64 q0, q1, q2, q3;
    #define ISSUE_Q(slot) { \
        const u64* p_ = (const u64*)(gb + (size_t)(slot) * 65536 \
                                     + (row_s << 8) + (cidx << 3)); \
        q0 = aload64(p_ + 0); q1 = aload64(p_ + 1); \
        q2 = aload64(p_ + 2); q3 = aload64(p_ + 3); }

    const int tend = ct0 + steps;
    if (ct0 > 0) ISSUE_Q((ct0 - 1) & 1);

    for (int t = ct0; t < tend; ++t){
        // prefetch xg (plain cached load, independent of sync)
        u16x4 xg4 = *(const u16x4*)(xg + ((size_t)(t - ct0) * 256 + r) * 1024
                                       + P0 + (l4 << 2));
        f32x4 a0 = {0,0,0,0}, a1 = {0,0,0,0};
        if (t > 0){
            const int slot = (t - 1) & 1;
            const u32 tg = (u32)(t - 1) & 0xffffu;
            // the load IS the sync: retry until all 8 tags fresh
            while (true){
                bool ok =
                    ((u32)q0 & 0xffffu) == tg && ((u32)(q0 >> 32) & 0xffffu) == tg &&
                    ((u32)q1 & 0xffffu) == tg && ((u32)(q1 >> 32) & 0xffffu) == tg &&
                    ((u32)q2 & 0xffffu) == tg && ((u32)(q2 >> 32) & 0xffffu) == tg &&
                    ((u32)q3 & 0xffffu) == tg && ((u32)(q3 >> 32) & 0xffffu) == tg;
                if (!__ballot(!ok)) break;
                __builtin_amdgcn_s_sleep(1);
                ISSUE_Q(slot);
            }
            // strip tags, stage into LDS (rotation layout: +row*48 mod 512)
            char* sbuf = lds + slot * 8192;
            u32 p0 = (u32)((q0 >> 16) & 0xffffu) | ((u32)(q0 >> 32) & 0xffff0000u);
            u32 p1 = (u32)((q1 >> 16) & 0xffffu) | ((u32)(q1 >> 32) & 0xffff0000u);
            u32 p2 = (u32)((q2 >> 16) & 0xffffu) | ((u32)(q2 >> 32) & 0xffff0000u);
            u32 p3 = (u32)((q3 >> 16) & 0xffffu) | ((u32)(q3 >> 32) & 0xffff0000u);
            *(u32x4*)(sbuf + (row_s << 9) + (((cidx << 4) + row_s * 48) & 511))
                = (u32x4){p0, p1, p2, p3};
            __syncthreads();
            // fragments + MFMA
            const char* rb = lds + slot * 8192 + (l15 << 9);
            const int rrot = l15 * 48;
            #pragma unroll
            for (int kf = 0; kf < 8; ++kf){
                int off = ((kf << 6) + (l4 << 4) + rrot) & 511;
                u16x8 hu = *(const u16x8*)(rb + off);
                bf16x8 hb = __builtin_bit_cast(bf16x8, hu);
                a0 = __builtin_amdgcn_mfma_f32_16x16x32_bf16(whi[kf], hb, a0, 0, 0, 0);
                a1 = __builtin_amdgcn_mfma_f32_16x16x32_bf16(wlo[kf], hb, a1, 0, 0, 0);
            }
        }
        float gs = bf2f(xg4[0]) + bias[0] + a0[0] + a1[0];
        float is = bf2f(xg4[1]) + bias[1] + a0[1] + a1[1];
        float fs = bf2f(xg4[2]) + bias[2] + a0[2] + a1[2];
        float os = bf2f(xg4[3]) + bias[3] + a0[3] + a1[3];
        float gv = tanhf_(gs);
        float iv = sigmoidf_(is);
        float fv = sigmoidf_(fs);
        float ov = sigmoidf_(os);
        c_val = gv * iv + c_val * fv;
        float hv = tanhf_(c_val) * ov;

        // tagged store: value + step tag in one atomic word
        u32 hp = ((u32)f2bf(hv) << 16) | ((u32)t & 0xffffu);
        __hip_atomic_store(h32 + (size_t)(t & 1) * 65536 + mb * 4096
                               + (l15 << 8) + hc,
                           hp, __ATOMIC_RELAXED, __HIP_MEMORY_SCOPE_AGENT);
        if (t == 1023) hT[(r << 8) + hc] = hv;

        // speculative prefetch of h[t] for next iteration (tags self-validate)
        if (t + 1 < tend) ISSUE_Q(t & 1);
    }
    if (tend < 1024) c_ws[(r << 8) + hc] = c_val;
    #undef ISSUE_Q
}

// ---------------------------------------------------------------------------
// Kernel 3: p = hT @ Wph + bph; softmax over 10.
// ---------------------------------------------------------------------------
__global__ __launch_bounds__(256) void lstm_head(
    const float* __restrict__ hT, const float* __restrict__ Wph,
    const float* __restrict__ bph, float* __restrict__ out)
{
    int b = threadIdx.x;
    float p[10];
    #pragma unroll
    for (int j = 0; j < 10; ++j) p[j] = bph[j];
    const float* hr = hT + (b << 8);
    for (int k = 0; k < 256; ++k){
        float h = hr[k];
        const float* wr = Wph + k * 10;
        #pragma unroll
        for (int j = 0; j < 10; ++j) p[j] += h * wr[j];
    }
    float m = p[0];
    #pragma unroll
    for (int j = 1; j < 10; ++j) m = fmaxf(m, p[j]);
    float s = 0.f;
    #pragma unroll
    for (int j = 0; j < 10; ++j){ p[j] = __expf(p[j] - m); s += p[j]; }
    float inv = 1.f / s;
    #pragma unroll
    for (int j = 0; j < 10; ++j) out[b * 10 + j] = p[j] * inv;
}

// ---------------------------------------------------------------------------
extern "C" void kernel_launch(void* const* d_in, const int* in_sizes, int n_in,
                              void* d_out, int out_size, void* d_ws, size_t ws_size,
                              hipStream_t stream)
{
    const float* x   = (const float*)d_in[0];
    const float* Wgx = (const float*)d_in[1];  const float* bgx = (const float*)d_in[2];
    const float* Wgh = (const float*)d_in[3];  const float* bgh = (const float*)d_in[4];
    const float* Wix = (const float*)d_in[5];  const float* bix = (const float*)d_in[6];
    const float* Wih = (const float*)d_in[7];  const float* bih = (const float*)d_in[8];
    const float* Wfx = (const float*)d_in[9];  const float* bfx = (const float*)d_in[10];
    const float* Wfh = (const float*)d_in[11]; const float* bfh = (const float*)d_in[12];
    const float* Wox = (const float*)d_in[13]; const float* box = (const float*)d_in[14];
    const float* Woh = (const float*)d_in[15]; const float* boh = (const float*)d_in[16];
    const float* Wph = (const float*)d_in[17]; const float* bph = (const float*)d_in[18];
    float* out = (float*)d_out;

    char* ws = (char*)d_ws;
    u32*   h32  = (u32*)  (ws + 0);            // [2][16][16][256] u32 = 512KB
    float* cws  = (float*)(ws + 524288);       // [256][256] f32 = 256KB
    float* hT   = (float*)(ws + 786432);       // [256][256] f32 = 256KB
    u16*   Wxpt = (u16*)  (ws + 1048576);      // [1024][128] bf16 = 256KB
    u16*   xgbuf= (u16*)  (ws + 1310720);      // [steps][256][1024] bf16
    size_t fixed = 1310720;
    size_t avail = ws_size > fixed ? ws_size - fixed : 0;
    long chunk = (long)(avail / 524288);       // 512KB per timestep
    if (chunk < 1) chunk = 1;
    if (chunk > 1024) chunk = 1024;

    lstm_pack<<<dim3(512), dim3(256), 0, stream>>>(Wgx, Wix, Wfx, Wox, Wxpt, h32);
    for (int ct0 = 0; ct0 < 1024; ct0 += (int)chunk){
        int steps = (int)((1024 - ct0 < chunk) ? (long)(1024 - ct0) : chunk);
        int mtiles = steps * 4;
        int mgroups = (mtiles + 15) / 16;
        lstm_xg<<<dim3(mgroups, 4), dim3(256), 0, stream>>>(
            x, Wxpt, xgbuf, ct0, steps, mtiles);
        lstm_rec<<<dim3(128), dim3(512), 0, stream>>>(
            xgbuf, Wgh, Wih, Wfh, Woh,
            bgx, bgh, bix, bih, bfx, bfh, box, boh,
            h32, cws, hT, ct0, steps);
    }
    lstm_head<<<dim3(1), dim3(256), 0, stream>>>(hT, Wph, bph, out);
}